// Round 17
// baseline (50.339 us; speedup 1.0000x reference)
//
#include <hip/hip_runtime.h>

#define TT 32768   // B*S tokens
#define S_LEN 1024
#define KC 16      // attention k-split chunks (64 rows each)

// intermediates; fully overwritten each call -> deterministic.
__device__ __align__(16) float g_Q[TT * 8];          // Q * 0.5 * log2(e)
__device__ __align__(16) float g_KV[64 * S_LEN * 8]; // [(b*2+h)*1024+k] -> {K4,V4}
__device__ __align__(16) float4 gp_acc[KC * 64 * 1024];
__device__ float gp_den[KC * 64 * 1024];
__device__ float g_coef[4][8][128];   // per-circuit uniform term coefficients

// ---------------------------------------------------------------------------
// Compile-time Pauli-backpropagation term tables (validated on HW in r11).
// ---------------------------------------------------------------------------
struct PTerm { unsigned ymask, zonly, tmask; float sgn; };
struct OTab { PTerm t[128]; int n; unsigned amask; };

constexpr unsigned conjZring(unsigned a) {
    for (int q = 7; q >= 0; --q) {
        const int c = q, tt = (q + 1) & 7;
        if ((a >> tt) & 1u) a ^= (1u << c);
    }
    return a;
}
constexpr unsigned conjXring(unsigned b) {
    for (int q = 7; q >= 0; --q) {
        const int c = q, tt = (q + 1) & 7;
        if ((b >> c) & 1u) b ^= (1u << tt);
    }
    return b;
}
constexpr int popc8(unsigned v) { int n = 0; for (int i = 0; i < 8; ++i) n += (v >> i) & 1; return n; }

constexpr OTab build_tab(int i) {
    OTab o{};
    o.n = 0;
    const unsigned a1 = conjZring(1u << i);
    o.amask = a1;
    const unsigned a3 = conjZring(a1);
    unsigned T = a1;
    while (true) {
        const unsigned b3 = conjXring(T);
        if (!(b3 & ~a3)) {
            const int k = popc8(T) + popc8(b3);
            const int idx = (k & 1) ? 100000 : o.n;   // odd phase => compile error
            o.t[idx].ymask = b3;
            o.t[idx].zonly = a3 & ~b3;
            o.t[idx].tmask = T;
            o.t[idx].sgn = ((k >> 1) & 1) ? -1.f : 1.f;
            o.n++;
        }
        if (T == 0) break;
        T = (T - 1) & a1;
    }
    return o;
}

constexpr OTab g_tab[8] = {build_tab(0), build_tab(1), build_tab(2), build_tab(3),
                           build_tab(4), build_tab(5), build_tab(6), build_tab(7)};
static_assert(g_tab[0].n >= 1 && g_tab[0].n <= 128, "term count");
static_assert(g_tab[7].n >= 1 && g_tab[7].n <= 128, "term count");

template <int I>
__device__ __forceinline__ void coef_one(const float s1[8], const float c1[8], float* dst)
{
    constexpr OTab tb = g_tab[I];
#pragma unroll
    for (int k = 0; k < tb.n; ++k) {
        float c = tb.t[k].sgn;
#pragma unroll
        for (int q = 0; q < 8; ++q) {
            if ((tb.t[k].tmask >> q) & 1) c *= s1[q];
            else if ((tb.amask >> q) & 1) c *= c1[q];
        }
        dst[k] = c;
    }
}

__global__ __launch_bounds__(64) void precoef(
    const float* __restrict__ wq, const float* __restrict__ wk,
    const float* __restrict__ wv, const float* __restrict__ wc)
{
    int tid = threadIdx.x;
    if (tid >= 32) return;
    int set = tid >> 3, i = tid & 7;
    const float* w = (set == 0) ? wq : (set == 1) ? wk : (set == 2) ? wv : wc;
    float s1[8], c1[8];
#pragma unroll
    for (int q = 0; q < 8; ++q) __sincosf(w[8 + q], &s1[q], &c1[q]);
    float* dst = &g_coef[set][i][0];
    switch (i) {
        case 0: coef_one<0>(s1, c1, dst); break;
        case 1: coef_one<1>(s1, c1, dst); break;
        case 2: coef_one<2>(s1, c1, dst); break;
        case 3: coef_one<3>(s1, c1, dst); break;
        case 4: coef_one<4>(s1, c1, dst); break;
        case 5: coef_one<5>(s1, c1, dst); break;
        case 6: coef_one<6>(s1, c1, dst); break;
        case 7: coef_one<7>(s1, c1, dst); break;
    }
}

template <int I>
__device__ __forceinline__ float eval_out(const float cs[8], const float sn[8],
                                          const float* __restrict__ coefI)
{
    constexpr OTab tb = g_tab[I];
    float acc = 0.f;
#pragma unroll
    for (int k = 0; k < tb.n; ++k) {
        float p = coefI[k];
#pragma unroll
        for (int q = 0; q < 8; ++q) {
            if ((tb.t[k].ymask >> q) & 1) p *= sn[q];
            else if ((tb.t[k].zonly >> q) & 1) p *= cs[q];
        }
        acc += p;
    }
    return acc;
}

__device__ __forceinline__ void eval_all(const float th[8],
                                         const float (*__restrict__ coef)[128],
                                         float ev[8])
{
    float cs[8], sn[8];
#pragma unroll
    for (int q = 0; q < 8; ++q) __sincosf(th[q], &sn[q], &cs[q]);
    ev[0] = eval_out<0>(cs, sn, coef[0]);
    ev[1] = eval_out<1>(cs, sn, coef[1]);
    ev[2] = eval_out<2>(cs, sn, coef[2]);
    ev[3] = eval_out<3>(cs, sn, coef[3]);
    ev[4] = eval_out<4>(cs, sn, coef[4]);
    ev[5] = eval_out<5>(cs, sn, coef[5]);
    ev[6] = eval_out<6>(cs, sn, coef[6]);
    ev[7] = eval_out<7>(cs, sn, coef[7]);
}

// Q is pre-scaled by 0.5*log2(e) so attention uses native v_exp_f32 (= exp2).
#define QSCALE 0.72134752044448170368f

// single-instruction exp2 on the trans pipe; non-volatile so it schedules.
__device__ __forceinline__ float fexp2(float s)
{
    float r;
    asm("v_exp_f32 %0, %1" : "=v"(r) : "v"(s));
    return r;
}

__global__ __launch_bounds__(256) void qkv_pauli(
    const float* __restrict__ x, const float* __restrict__ wq,
    const float* __restrict__ wk, const float* __restrict__ wv)
{
    int t = blockIdx.x * 256 + threadIdx.x;
    int set = blockIdx.y;
    const float* w = (set == 0) ? wq : (set == 1) ? wk : wv;
    float4 xa = ((const float4*)x)[t * 2];
    float4 xb = ((const float4*)x)[t * 2 + 1];
    float th[8] = {xa.x + w[0], xa.y + w[1], xa.z + w[2], xa.w + w[3],
                   xb.x + w[4], xb.y + w[5], xb.z + w[6], xb.w + w[7]};
    float ev[8];
    eval_all(th, g_coef[set], ev);
    if (set == 0) {
#pragma unroll
        for (int i = 0; i < 8; ++i) ev[i] *= QSCALE;
        ((float4*)g_Q)[t * 2]     = make_float4(ev[0], ev[1], ev[2], ev[3]);
        ((float4*)g_Q)[t * 2 + 1] = make_float4(ev[4], ev[5], ev[6], ev[7]);
    } else {
        // packed K/V rows: g_KV[((b*2+h)*S_LEN + s)*8 + {0..3 K, 4..7 V}]
        int b = t >> 10, s = t & 1023;
        float* d0 = g_KV + ((size_t)(b * 2) * S_LEN + s) * 8 + ((set == 1) ? 0 : 4);
        *(float4*)d0                 = make_float4(ev[0], ev[1], ev[2], ev[3]);  // h=0
        *(float4*)(d0 + S_LEN * 8)   = make_float4(ev[4], ev[5], ev[6], ev[7]);  // h=1
    }
}

// ---------------------------------------------------------------------------
// attention: NO LDS, NO barrier. K/V read as wave-uniform float4s from the
// packed g_KV (scalarizable loads; 2 KB/chunk L1-resident). 4 q-chains per
// thread; grid (64 bh, 16 kc) = 1024 blocks = 4 blk/CU, 16 waves/CU.
// ---------------------------------------------------------------------------
__global__ __launch_bounds__(256, 4) void attn_part()
{
    int bh = blockIdx.x, kc = blockIdx.y;
    int b = bh >> 1, h = bh & 1;
    int tid = threadIdx.x;

    const float* Qb = g_Q + (size_t)b * S_LEN * 8 + h * 4;
    float4 qv0 = *(const float4*)(Qb + (size_t)(tid      ) * 8);
    float4 qv1 = *(const float4*)(Qb + (size_t)(tid + 256) * 8);
    float4 qv2 = *(const float4*)(Qb + (size_t)(tid + 512) * 8);
    float4 qv3 = *(const float4*)(Qb + (size_t)(tid + 768) * 8);

    const float* KV = g_KV + ((size_t)bh * S_LEN + kc * 64) * 8;

    float den0 = 0.f, den1 = 0.f, den2 = 0.f, den3 = 0.f;
    float4 ac0 = make_float4(0.f, 0.f, 0.f, 0.f);
    float4 ac1 = make_float4(0.f, 0.f, 0.f, 0.f);
    float4 ac2 = make_float4(0.f, 0.f, 0.f, 0.f);
    float4 ac3 = make_float4(0.f, 0.f, 0.f, 0.f);
#pragma unroll 4
    for (int k = 0; k < 64; ++k) {
        float4 kk = *(const float4*)(KV + (size_t)k * 8);      // wave-uniform
        float4 vv = *(const float4*)(KV + (size_t)k * 8 + 4);  // wave-uniform
        float s0 = qv0.x * kk.x + qv0.y * kk.y + qv0.z * kk.z + qv0.w * kk.w;
        float s1 = qv1.x * kk.x + qv1.y * kk.y + qv1.z * kk.z + qv1.w * kk.w;
        float s2 = qv2.x * kk.x + qv2.y * kk.y + qv2.z * kk.z + qv2.w * kk.w;
        float s3 = qv3.x * kk.x + qv3.y * kk.y + qv3.z * kk.z + qv3.w * kk.w;
        float e0 = fexp2(s0);
        float e1 = fexp2(s1);
        float e2 = fexp2(s2);
        float e3 = fexp2(s3);
        den0 += e0; den1 += e1; den2 += e2; den3 += e3;
        ac0.x += e0 * vv.x; ac0.y += e0 * vv.y; ac0.z += e0 * vv.z; ac0.w += e0 * vv.w;
        ac1.x += e1 * vv.x; ac1.y += e1 * vv.y; ac1.z += e1 * vv.z; ac1.w += e1 * vv.w;
        ac2.x += e2 * vv.x; ac2.y += e2 * vv.y; ac2.z += e2 * vv.z; ac2.w += e2 * vv.w;
        ac3.x += e3 * vv.x; ac3.y += e3 * vv.y; ac3.z += e3 * vv.z; ac3.w += e3 * vv.w;
    }
    int base = kc * 65536 + bh * 1024 + tid;
    gp_acc[base]       = ac0;  gp_den[base]       = den0;
    gp_acc[base + 256] = ac1;  gp_den[base + 256] = den1;
    gp_acc[base + 512] = ac2;  gp_den[base + 512] = den2;
    gp_acc[base + 768] = ac3;  gp_den[base + 768] = den3;
}

// ---- output circuit with fused k-split merge ----
__global__ __launch_bounds__(256) void outc_pauli(
    const float* __restrict__ wc, float* __restrict__ out)
{
    int t = blockIdx.x * 256 + threadIdx.x;
    int b = t >> 10, s = t & 1023;
    float th[8];
#pragma unroll
    for (int h = 0; h < 2; ++h) {
        float4 A = make_float4(0.f, 0.f, 0.f, 0.f);
        float D = 0.f;
#pragma unroll
        for (int kc = 0; kc < KC; ++kc) {
            int idx = kc * 65536 + (b * 2 + h) * 1024 + s;
            float4 a = gp_acc[idx];
            A.x += a.x; A.y += a.y; A.z += a.z; A.w += a.w;
            D += gp_den[idx];
        }
        float inv = 1.f / D;
        th[h * 4 + 0] = A.x * inv + wc[h * 4 + 0];
        th[h * 4 + 1] = A.y * inv + wc[h * 4 + 1];
        th[h * 4 + 2] = A.z * inv + wc[h * 4 + 2];
        th[h * 4 + 3] = A.w * inv + wc[h * 4 + 3];
    }
    float ev[8];
    eval_all(th, g_coef[3], ev);
    ((float4*)out)[t * 2]     = make_float4(ev[0], ev[1], ev[2], ev[3]);
    ((float4*)out)[t * 2 + 1] = make_float4(ev[4], ev[5], ev[6], ev[7]);
}

extern "C" void kernel_launch(void* const* d_in, const int* in_sizes, int n_in,
                              void* d_out, int out_size, void* d_ws, size_t ws_size,
                              hipStream_t stream)
{
    const float* x  = (const float*)d_in[0];
    const float* wq = (const float*)d_in[1];
    const float* wk = (const float*)d_in[2];
    const float* wv = (const float*)d_in[3];
    const float* wc = (const float*)d_in[4];

    precoef<<<1, 64, 0, stream>>>(wq, wk, wv, wc);
    qkv_pauli<<<dim3(TT / 256, 3), 256, 0, stream>>>(x, wq, wk, wv);
    attn_part<<<dim3(64, KC), 256, 0, stream>>>();
    outc_pauli<<<TT / 256, 256, 0, stream>>>(wc, (float*)d_out);
}

// Round 18
// 49.927 us; speedup vs baseline: 1.0083x; 1.0083x over previous
//
#include <hip/hip_runtime.h>

#define TT 32768   // B*S tokens
#define S_LEN 1024
#define KC 16      // attention k-split chunks (64 rows each)

// intermediates; fully overwritten each call -> deterministic.
__device__ __align__(16) float g_Q[TT * 8];   // holds Q * 0.5 * log2(e)
__device__ __align__(16) float g_K[TT * 8];
__device__ __align__(16) float g_V[TT * 8];
__device__ __align__(16) float4 gp_acc[KC * 64 * 1024];
__device__ float gp_den[KC * 64 * 1024];
__device__ float g_coef[4][8][128];   // per-circuit uniform term coefficients

// ---------------------------------------------------------------------------
// Compile-time Pauli-backpropagation term tables (validated on HW in r11).
// ---------------------------------------------------------------------------
struct PTerm { unsigned ymask, zonly, tmask; float sgn; };
struct OTab { PTerm t[128]; int n; unsigned amask; };

constexpr unsigned conjZring(unsigned a) {
    for (int q = 7; q >= 0; --q) {
        const int c = q, tt = (q + 1) & 7;
        if ((a >> tt) & 1u) a ^= (1u << c);
    }
    return a;
}
constexpr unsigned conjXring(unsigned b) {
    for (int q = 7; q >= 0; --q) {
        const int c = q, tt = (q + 1) & 7;
        if ((b >> c) & 1u) b ^= (1u << tt);
    }
    return b;
}
constexpr int popc8(unsigned v) { int n = 0; for (int i = 0; i < 8; ++i) n += (v >> i) & 1; return n; }

constexpr OTab build_tab(int i) {
    OTab o{};
    o.n = 0;
    const unsigned a1 = conjZring(1u << i);
    o.amask = a1;
    const unsigned a3 = conjZring(a1);
    unsigned T = a1;
    while (true) {
        const unsigned b3 = conjXring(T);
        if (!(b3 & ~a3)) {
            const int k = popc8(T) + popc8(b3);
            const int idx = (k & 1) ? 100000 : o.n;   // odd phase => compile error
            o.t[idx].ymask = b3;
            o.t[idx].zonly = a3 & ~b3;
            o.t[idx].tmask = T;
            o.t[idx].sgn = ((k >> 1) & 1) ? -1.f : 1.f;
            o.n++;
        }
        if (T == 0) break;
        T = (T - 1) & a1;
    }
    return o;
}

constexpr OTab g_tab[8] = {build_tab(0), build_tab(1), build_tab(2), build_tab(3),
                           build_tab(4), build_tab(5), build_tab(6), build_tab(7)};
static_assert(g_tab[0].n >= 1 && g_tab[0].n <= 128, "term count");
static_assert(g_tab[7].n >= 1 && g_tab[7].n <= 128, "term count");

template <int I>
__device__ __forceinline__ void coef_one(const float s1[8], const float c1[8], float* dst)
{
    constexpr OTab tb = g_tab[I];
#pragma unroll
    for (int k = 0; k < tb.n; ++k) {
        float c = tb.t[k].sgn;
#pragma unroll
        for (int q = 0; q < 8; ++q) {
            if ((tb.t[k].tmask >> q) & 1) c *= s1[q];
            else if ((tb.amask >> q) & 1) c *= c1[q];
        }
        dst[k] = c;
    }
}

__global__ __launch_bounds__(64) void precoef(
    const float* __restrict__ wq, const float* __restrict__ wk,
    const float* __restrict__ wv, const float* __restrict__ wc)
{
    int tid = threadIdx.x;
    if (tid >= 32) return;
    int set = tid >> 3, i = tid & 7;
    const float* w = (set == 0) ? wq : (set == 1) ? wk : (set == 2) ? wv : wc;
    float s1[8], c1[8];
#pragma unroll
    for (int q = 0; q < 8; ++q) __sincosf(w[8 + q], &s1[q], &c1[q]);
    float* dst = &g_coef[set][i][0];
    switch (i) {
        case 0: coef_one<0>(s1, c1, dst); break;
        case 1: coef_one<1>(s1, c1, dst); break;
        case 2: coef_one<2>(s1, c1, dst); break;
        case 3: coef_one<3>(s1, c1, dst); break;
        case 4: coef_one<4>(s1, c1, dst); break;
        case 5: coef_one<5>(s1, c1, dst); break;
        case 6: coef_one<6>(s1, c1, dst); break;
        case 7: coef_one<7>(s1, c1, dst); break;
    }
}

template <int I>
__device__ __forceinline__ float eval_out(const float cs[8], const float sn[8],
                                          const float* __restrict__ coefI)
{
    constexpr OTab tb = g_tab[I];
    float acc = 0.f;
#pragma unroll
    for (int k = 0; k < tb.n; ++k) {
        float p = coefI[k];
#pragma unroll
        for (int q = 0; q < 8; ++q) {
            if ((tb.t[k].ymask >> q) & 1) p *= sn[q];
            else if ((tb.t[k].zonly >> q) & 1) p *= cs[q];
        }
        acc += p;
    }
    return acc;
}

__device__ __forceinline__ void eval_all(const float th[8],
                                         const float (*__restrict__ coef)[128],
                                         float ev[8])
{
    float cs[8], sn[8];
#pragma unroll
    for (int q = 0; q < 8; ++q) __sincosf(th[q], &sn[q], &cs[q]);
    ev[0] = eval_out<0>(cs, sn, coef[0]);
    ev[1] = eval_out<1>(cs, sn, coef[1]);
    ev[2] = eval_out<2>(cs, sn, coef[2]);
    ev[3] = eval_out<3>(cs, sn, coef[3]);
    ev[4] = eval_out<4>(cs, sn, coef[4]);
    ev[5] = eval_out<5>(cs, sn, coef[5]);
    ev[6] = eval_out<6>(cs, sn, coef[6]);
    ev[7] = eval_out<7>(cs, sn, coef[7]);
}

// Q is pre-scaled by 0.5*log2(e) so attention uses native v_exp_f32 (= exp2).
#define QSCALE 0.72134752044448170368f

// single-instruction exp2 on the trans pipe; non-volatile so it schedules.
__device__ __forceinline__ float fexp2(float s)
{
    float r;
    asm("v_exp_f32 %0, %1" : "=v"(r) : "v"(s));
    return r;
}

__global__ __launch_bounds__(256) void qkv_pauli(
    const float* __restrict__ x, const float* __restrict__ wq,
    const float* __restrict__ wk, const float* __restrict__ wv)
{
    int t = blockIdx.x * 256 + threadIdx.x;
    int set = blockIdx.y;
    const float* w = (set == 0) ? wq : (set == 1) ? wk : wv;
    float* out = (set == 0) ? g_Q : (set == 1) ? g_K : g_V;
    float4 xa = ((const float4*)x)[t * 2];
    float4 xb = ((const float4*)x)[t * 2 + 1];
    float th[8] = {xa.x + w[0], xa.y + w[1], xa.z + w[2], xa.w + w[3],
                   xb.x + w[4], xb.y + w[5], xb.z + w[6], xb.w + w[7]};
    float ev[8];
    eval_all(th, g_coef[set], ev);
    float sc = (set == 0) ? QSCALE : 1.f;
#pragma unroll
    for (int i = 0; i < 8; ++i) ev[i] *= sc;
    ((float4*)out)[t * 2]     = make_float4(ev[0], ev[1], ev[2], ev[3]);
    ((float4*)out)[t * 2 + 1] = make_float4(ev[4], ev[5], ev[6], ev[7]);
}

// ---------------------------------------------------------------------------
// attention: block = 128 threads, EIGHT q-chains per thread (covers all
// 1024 q of one (b,h)); chunk = 64 k-rows; grid (64 bh, 16 kc) = 1024
// blocks = exactly 4 blocks/CU, ALL co-resident (no tail), 8 waves/CU.
// Wave DS-reads: 2 per 8 q-chains per k -> 262k total = ~5 us DS floor;
// 8 independent dot->exp->acc chains fill VALU latency.
// ---------------------------------------------------------------------------
__global__ __launch_bounds__(128, 2) void attn_part()
{
    __shared__ float4 Ks[64];
    __shared__ float4 Vs[64];
    int bh = blockIdx.x, kc = blockIdx.y;
    int b = bh >> 1, h = bh & 1;
    int tid = threadIdx.x;

    const float* Qb = g_Q + (size_t)b * S_LEN * 8 + h * 4;
    float4 qv[8];
#pragma unroll
    for (int c = 0; c < 8; ++c)
        qv[c] = *(const float4*)(Qb + (size_t)(tid + c * 128) * 8);

    size_t rowbase = (size_t)b * S_LEN + kc * 64;
    if (tid < 64) {
        Ks[tid] = *(const float4*)(g_K + (rowbase + tid) * 8 + h * 4);
    } else {
        int r = tid - 64;
        Vs[r] = *(const float4*)(g_V + (rowbase + r) * 8 + h * 4);
    }
    __syncthreads();

    float den[8];
    float4 ac[8];
#pragma unroll
    for (int c = 0; c < 8; ++c) {
        den[c] = 0.f;
        ac[c] = make_float4(0.f, 0.f, 0.f, 0.f);
    }
#pragma unroll 2
    for (int k = 0; k < 64; ++k) {
        float4 kk = Ks[k];
        float4 vv = Vs[k];
#pragma unroll
        for (int c = 0; c < 8; ++c) {
            float s = qv[c].x * kk.x + qv[c].y * kk.y + qv[c].z * kk.z + qv[c].w * kk.w;
            float e = fexp2(s);
            den[c] += e;
            ac[c].x += e * vv.x; ac[c].y += e * vv.y;
            ac[c].z += e * vv.z; ac[c].w += e * vv.w;
        }
    }
    int base = kc * 65536 + bh * 1024 + tid;
#pragma unroll
    for (int c = 0; c < 8; ++c) {
        gp_acc[base + c * 128] = ac[c];
        gp_den[base + c * 128] = den[c];
    }
}

// ---- output circuit with fused k-split merge ----
__global__ __launch_bounds__(256) void outc_pauli(
    const float* __restrict__ wc, float* __restrict__ out)
{
    int t = blockIdx.x * 256 + threadIdx.x;
    int b = t >> 10, s = t & 1023;
    float th[8];
#pragma unroll
    for (int h = 0; h < 2; ++h) {
        float4 A = make_float4(0.f, 0.f, 0.f, 0.f);
        float D = 0.f;
#pragma unroll
        for (int kc = 0; kc < KC; ++kc) {
            int idx = kc * 65536 + (b * 2 + h) * 1024 + s;
            float4 a = gp_acc[idx];
            A.x += a.x; A.y += a.y; A.z += a.z; A.w += a.w;
            D += gp_den[idx];
        }
        float inv = 1.f / D;
        th[h * 4 + 0] = A.x * inv + wc[h * 4 + 0];
        th[h * 4 + 1] = A.y * inv + wc[h * 4 + 1];
        th[h * 4 + 2] = A.z * inv + wc[h * 4 + 2];
        th[h * 4 + 3] = A.w * inv + wc[h * 4 + 3];
    }
    float ev[8];
    eval_all(th, g_coef[3], ev);
    ((float4*)out)[t * 2]     = make_float4(ev[0], ev[1], ev[2], ev[3]);
    ((float4*)out)[t * 2 + 1] = make_float4(ev[4], ev[5], ev[6], ev[7]);
}

extern "C" void kernel_launch(void* const* d_in, const int* in_sizes, int n_in,
                              void* d_out, int out_size, void* d_ws, size_t ws_size,
                              hipStream_t stream)
{
    const float* x  = (const float*)d_in[0];
    const float* wq = (const float*)d_in[1];
    const float* wk = (const float*)d_in[2];
    const float* wv = (const float*)d_in[3];
    const float* wc = (const float*)d_in[4];

    precoef<<<1, 64, 0, stream>>>(wq, wk, wv, wc);
    qkv_pauli<<<dim3(TT / 256, 3), 256, 0, stream>>>(x, wq, wk, wv);
    attn_part<<<dim3(64, KC), 128, 0, stream>>>();
    outc_pauli<<<TT / 256, 256, 0, stream>>>(wc, (float*)d_out);
}

// Round 19
// 45.807 us; speedup vs baseline: 1.0989x; 1.0899x over previous
//
#include <hip/hip_runtime.h>

#define TT 32768   // B*S tokens
#define S_LEN 1024

typedef __attribute__((ext_vector_type(8))) short short8;
typedef __attribute__((ext_vector_type(16))) float f32x16;

// intermediates; fully overwritten each call -> deterministic.
__device__ __align__(16) short g_Qb[64 * 1024 * 8];  // [bh][q][8] bf16 (Q*QSCALE, 4 real + 4 pad)
__device__ __align__(16) short g_Kb[64 * 1024 * 8];  // [bh][k][8] bf16 padded
__device__ __align__(16) short g_Vt[64 * 4 * 1024];  // [bh][d][k] bf16 (V transposed)
__device__ __align__(16) float g_C[TT * 8];
__device__ float g_coef[4][8][128];

// ---------------------------------------------------------------------------
// Compile-time Pauli-backpropagation term tables (validated on HW in r11).
// ---------------------------------------------------------------------------
struct PTerm { unsigned ymask, zonly, tmask; float sgn; };
struct OTab { PTerm t[128]; int n; unsigned amask; };

constexpr unsigned conjZring(unsigned a) {
    for (int q = 7; q >= 0; --q) {
        const int c = q, tt = (q + 1) & 7;
        if ((a >> tt) & 1u) a ^= (1u << c);
    }
    return a;
}
constexpr unsigned conjXring(unsigned b) {
    for (int q = 7; q >= 0; --q) {
        const int c = q, tt = (q + 1) & 7;
        if ((b >> c) & 1u) b ^= (1u << tt);
    }
    return b;
}
constexpr int popc8(unsigned v) { int n = 0; for (int i = 0; i < 8; ++i) n += (v >> i) & 1; return n; }

constexpr OTab build_tab(int i) {
    OTab o{};
    o.n = 0;
    const unsigned a1 = conjZring(1u << i);
    o.amask = a1;
    const unsigned a3 = conjZring(a1);
    unsigned T = a1;
    while (true) {
        const unsigned b3 = conjXring(T);
        if (!(b3 & ~a3)) {
            const int k = popc8(T) + popc8(b3);
            const int idx = (k & 1) ? 100000 : o.n;   // odd phase => compile error
            o.t[idx].ymask = b3;
            o.t[idx].zonly = a3 & ~b3;
            o.t[idx].tmask = T;
            o.t[idx].sgn = ((k >> 1) & 1) ? -1.f : 1.f;
            o.n++;
        }
        if (T == 0) break;
        T = (T - 1) & a1;
    }
    return o;
}

constexpr OTab g_tab[8] = {build_tab(0), build_tab(1), build_tab(2), build_tab(3),
                           build_tab(4), build_tab(5), build_tab(6), build_tab(7)};
static_assert(g_tab[0].n >= 1 && g_tab[0].n <= 128, "term count");
static_assert(g_tab[7].n >= 1 && g_tab[7].n <= 128, "term count");

template <int I>
__device__ __forceinline__ void coef_one(const float s1[8], const float c1[8], float* dst)
{
    constexpr OTab tb = g_tab[I];
#pragma unroll
    for (int k = 0; k < tb.n; ++k) {
        float c = tb.t[k].sgn;
#pragma unroll
        for (int q = 0; q < 8; ++q) {
            if ((tb.t[k].tmask >> q) & 1) c *= s1[q];
            else if ((tb.amask >> q) & 1) c *= c1[q];
        }
        dst[k] = c;
    }
}

__global__ __launch_bounds__(64) void precoef(
    const float* __restrict__ wq, const float* __restrict__ wk,
    const float* __restrict__ wv, const float* __restrict__ wc)
{
    int tid = threadIdx.x;
    if (tid >= 32) return;
    int set = tid >> 3, i = tid & 7;
    const float* w = (set == 0) ? wq : (set == 1) ? wk : (set == 2) ? wv : wc;
    float s1[8], c1[8];
#pragma unroll
    for (int q = 0; q < 8; ++q) __sincosf(w[8 + q], &s1[q], &c1[q]);
    float* dst = &g_coef[set][i][0];
    switch (i) {
        case 0: coef_one<0>(s1, c1, dst); break;
        case 1: coef_one<1>(s1, c1, dst); break;
        case 2: coef_one<2>(s1, c1, dst); break;
        case 3: coef_one<3>(s1, c1, dst); break;
        case 4: coef_one<4>(s1, c1, dst); break;
        case 5: coef_one<5>(s1, c1, dst); break;
        case 6: coef_one<6>(s1, c1, dst); break;
        case 7: coef_one<7>(s1, c1, dst); break;
    }
}

template <int I>
__device__ __forceinline__ float eval_out(const float cs[8], const float sn[8],
                                          const float* __restrict__ coefI)
{
    constexpr OTab tb = g_tab[I];
    float acc = 0.f;
#pragma unroll
    for (int k = 0; k < tb.n; ++k) {
        float p = coefI[k];
#pragma unroll
        for (int q = 0; q < 8; ++q) {
            if ((tb.t[k].ymask >> q) & 1) p *= sn[q];
            else if ((tb.t[k].zonly >> q) & 1) p *= cs[q];
        }
        acc += p;
    }
    return acc;
}

__device__ __forceinline__ void eval_all(const float th[8],
                                         const float (*__restrict__ coef)[128],
                                         float ev[8])
{
    float cs[8], sn[8];
#pragma unroll
    for (int q = 0; q < 8; ++q) __sincosf(th[q], &sn[q], &cs[q]);
    ev[0] = eval_out<0>(cs, sn, coef[0]);
    ev[1] = eval_out<1>(cs, sn, coef[1]);
    ev[2] = eval_out<2>(cs, sn, coef[2]);
    ev[3] = eval_out<3>(cs, sn, coef[3]);
    ev[4] = eval_out<4>(cs, sn, coef[4]);
    ev[5] = eval_out<5>(cs, sn, coef[5]);
    ev[6] = eval_out<6>(cs, sn, coef[6]);
    ev[7] = eval_out<7>(cs, sn, coef[7]);
}

// Q pre-scaled by 0.5*log2(e): attention exponent uses native v_exp (exp2).
#define QSCALE 0.72134752044448170368f

__device__ __forceinline__ float fexp2(float s)
{
    float r;
    asm("v_exp_f32 %0, %1" : "=v"(r) : "v"(s));
    return r;
}

// f32 -> bf16 (RNE), dependency-free
__device__ __forceinline__ short f2bf(float f)
{
    unsigned u = __float_as_uint(f);
    unsigned r = (u + 0x7FFFu + ((u >> 16) & 1u)) >> 16;
    return (short)r;
}

__global__ __launch_bounds__(256) void qkv_pauli(
    const float* __restrict__ x, const float* __restrict__ wq,
    const float* __restrict__ wk, const float* __restrict__ wv)
{
    int t = blockIdx.x * 256 + threadIdx.x;
    int set = blockIdx.y;
    const float* w = (set == 0) ? wq : (set == 1) ? wk : wv;
    float4 xa = ((const float4*)x)[t * 2];
    float4 xb = ((const float4*)x)[t * 2 + 1];
    float th[8] = {xa.x + w[0], xa.y + w[1], xa.z + w[2], xa.w + w[3],
                   xb.x + w[4], xb.y + w[5], xb.z + w[6], xb.w + w[7]};
    float ev[8];
    eval_all(th, g_coef[set], ev);

    int b = t >> 10, s = t & 1023;
    if (set == 2) {
        // V transposed: g_Vt[(bh*4+d)*1024 + s]
#pragma unroll
        for (int h = 0; h < 2; ++h)
#pragma unroll
            for (int d = 0; d < 4; ++d)
                g_Vt[((size_t)((b * 2 + h) * 4 + d)) * 1024 + s] = f2bf(ev[h * 4 + d]);
    } else {
        short* dst = (set == 0) ? g_Qb : g_Kb;
        float sc = (set == 0) ? QSCALE : 1.f;
#pragma unroll
        for (int h = 0; h < 2; ++h) {
            short8 row;
            row[0] = f2bf(ev[h * 4 + 0] * sc);
            row[1] = f2bf(ev[h * 4 + 1] * sc);
            row[2] = f2bf(ev[h * 4 + 2] * sc);
            row[3] = f2bf(ev[h * 4 + 3] * sc);
            row[4] = 0; row[5] = 0; row[6] = 0; row[7] = 0;
            *(short8*)(dst + ((size_t)(b * 2 + h) * 1024 + s) * 8) = row;
        }
    }
}

// ---------------------------------------------------------------------------
// MFMA attention. One wave = one (bh, 32-q block); k-loop in 32-chunks.
//  1) S^T = mfma32x32x16(A=K-rows, B=Q^T)  [K-dim mapping cancels A vs B]
//  2) p = exp2(S^T)  (16 trans/lane; C-layout row=(r&3)+8(r>>2)+4hi, col=q=lane&31)
//  3) P^T -> B-frag: 8 cvt_pk + 4 permlane32_swap (guide T12/§B recipe)
//  4) ctx^T = mfma(A=V^T rows + ones-row-4, B=P^T) x2 (k' 0..15 / 16..31),
//     accumulated in one f32x16 across all chunks; den = row 4 (free).
// No LDS, no barrier, no k-split partials, no merge.
// ---------------------------------------------------------------------------
__global__ __launch_bounds__(256) void attn_mfma()
{
    int lane = threadIdx.x & 63;
    int gw = blockIdx.x * 4 + (threadIdx.x >> 6);
    int bh = gw >> 5, qblk = gw & 31;
    int l31 = lane & 31, hi = lane >> 5;

    short8 zero8 = {0, 0, 0, 0, 0, 0, 0, 0};
    short8 ones8 = {0x3F80, 0x3F80, 0x3F80, 0x3F80, 0x3F80, 0x3F80, 0x3F80, 0x3F80};

    short8 qf = zero8;
    if (lane < 32)
        qf = *(const short8*)(g_Qb + ((size_t)bh * 1024 + qblk * 32 + l31) * 8);

    f32x16 acc;
#pragma unroll
    for (int r = 0; r < 16; ++r) acc[r] = 0.f;

    for (int kc = 0; kc < 32; ++kc) {
        short8 kf = zero8;
        if (lane < 32)
            kf = *(const short8*)(g_Kb + ((size_t)bh * 1024 + kc * 32 + l31) * 8);

        f32x16 zc;
#pragma unroll
        for (int r = 0; r < 16; ++r) zc[r] = 0.f;
        f32x16 c1 = __builtin_amdgcn_mfma_f32_32x32x16_bf16(kf, qf, zc, 0, 0, 0);

        float p[16];
#pragma unroll
        for (int r = 0; r < 16; ++r) p[r] = fexp2(c1[r]);

        unsigned w0, w1, w2, w3, w4, w5, w6, w7;
        asm("v_cvt_pk_bf16_f32 %0, %1, %2" : "=v"(w0) : "v"(p[0]),  "v"(p[1]));
        asm("v_cvt_pk_bf16_f32 %0, %1, %2" : "=v"(w1) : "v"(p[2]),  "v"(p[3]));
        asm("v_cvt_pk_bf16_f32 %0, %1, %2" : "=v"(w2) : "v"(p[4]),  "v"(p[5]));
        asm("v_cvt_pk_bf16_f32 %0, %1, %2" : "=v"(w3) : "v"(p[6]),  "v"(p[7]));
        asm("v_cvt_pk_bf16_f32 %0, %1, %2" : "=v"(w4) : "v"(p[8]),  "v"(p[9]));
        asm("v_cvt_pk_bf16_f32 %0, %1, %2" : "=v"(w5) : "v"(p[10]), "v"(p[11]));
        asm("v_cvt_pk_bf16_f32 %0, %1, %2" : "=v"(w6) : "v"(p[12]), "v"(p[13]));
        asm("v_cvt_pk_bf16_f32 %0, %1, %2" : "=v"(w7) : "v"(p[14]), "v"(p[15]));
        // halves exchange across lane<32 / lane>=32 (one swap fills two words)
        asm("v_permlane32_swap_b32 %0, %1" : "+v"(w0), "+v"(w2));
        asm("v_permlane32_swap_b32 %0, %1" : "+v"(w1), "+v"(w3));
        asm("v_permlane32_swap_b32 %0, %1" : "+v"(w4), "+v"(w6));
        asm("v_permlane32_swap_b32 %0, %1" : "+v"(w5), "+v"(w7));

        union { unsigned u[4]; short8 s8; } ba, bb;
        ba.u[0] = w0; ba.u[1] = w1; ba.u[2] = w2; ba.u[3] = w3;
        bb.u[0] = w4; bb.u[1] = w5; bb.u[2] = w6; bb.u[3] = w7;

        short8 va = zero8, vb = zero8;
        if (l31 < 4) {
            const short* vp = g_Vt + ((size_t)bh * 4 + l31) * 1024 + kc * 32 + hi * 8;
            va = *(const short8*)(vp);
            vb = *(const short8*)(vp + 16);
        } else if (l31 == 4) {
            va = ones8;   // ones row -> den accumulates in C row 4
            vb = ones8;
        }
        acc = __builtin_amdgcn_mfma_f32_32x32x16_bf16(va, ba.s8, acc, 0, 0, 0);
        acc = __builtin_amdgcn_mfma_f32_32x32x16_bf16(vb, bb.s8, acc, 0, 0, 0);
    }

    // den lives at lanes>=32, reg 0 (row 4). Exchange robust to swap semantics:
    float t0 = acc[0], t1 = acc[0];
    asm("v_permlane32_swap_b32 %0, %1" : "+v"(t0), "+v"(t1));
    float den = t0 + t1 - acc[0];      // valid for lanes<32
    if (lane < 32) {
        float inv = 1.f / den;
        int b = bh >> 1, h = bh & 1;
        float* cp = g_C + ((size_t)b * 1024 + qblk * 32 + l31) * 8 + h * 4;
        cp[0] = acc[0] * inv;
        cp[1] = acc[1] * inv;
        cp[2] = acc[2] * inv;
        cp[3] = acc[3] * inv;
    }
}

// ---- output circuit (reads g_C directly; no partials/merge anymore) ----
__global__ __launch_bounds__(256) void outc_pauli(
    const float* __restrict__ wc, float* __restrict__ out)
{
    int t = blockIdx.x * 256 + threadIdx.x;
    float4 ca = ((const float4*)g_C)[t * 2];
    float4 cb = ((const float4*)g_C)[t * 2 + 1];
    float th[8] = {ca.x + wc[0], ca.y + wc[1], ca.z + wc[2], ca.w + wc[3],
                   cb.x + wc[4], cb.y + wc[5], cb.z + wc[6], cb.w + wc[7]};
    float ev[8];
    eval_all(th, g_coef[3], ev);
    ((float4*)out)[t * 2]     = make_float4(ev[0], ev[1], ev[2], ev[3]);
    ((float4*)out)[t * 2 + 1] = make_float4(ev[4], ev[5], ev[6], ev[7]);
}

extern "C" void kernel_launch(void* const* d_in, const int* in_sizes, int n_in,
                              void* d_out, int out_size, void* d_ws, size_t ws_size,
                              hipStream_t stream)
{
    const float* x  = (const float*)d_in[0];
    const float* wq = (const float*)d_in[1];
    const float* wk = (const float*)d_in[2];
    const float* wv = (const float*)d_in[3];
    const float* wc = (const float*)d_in[4];

    precoef<<<1, 64, 0, stream>>>(wq, wk, wv, wc);
    qkv_pauli<<<dim3(TT / 256, 3), 256, 0, stream>>>(x, wq, wk, wv);
    attn_mfma<<<512, 256, 0, stream>>>();
    outc_pauli<<<TT / 256, 256, 0, stream>>>(wc, (float*)d_out);
}